// Round 8
// baseline (31.590 us; speedup 1.0000x reference)
//
#include <hip/hip_runtime.h>

#define T_STEPS 2048
#define NI 4096
#define NO 4096

static constexpr float BETA = 0.9f;
static constexpr float THRESH = 1.0f;

#define SPK_FLOATS ((unsigned)T_STEPS * (unsigned)NO)      // 8,388,608
#define SPK_VEC4   (SPK_FLOATS / 4u)                       // 2,097,152
#define TOT_VEC4   (2u * SPK_VEC4)                         // 4,194,304
#define Z4TOT      (TOT_VEC4 - 1024u)                      // skip mem row 0

typedef float f4 __attribute__((ext_vector_type(4)));

// Workspace: just cur0. Fully rewritten every call (no stale-state reliance).
struct Ws {
  float cur0[NO]; // cur at t=0 = x[0]·W[o]
};

// ---- Threefry-2x32, key = (0, 42), matching JAX's threefry2x32 ----
__device__ inline void threefry2x32(unsigned k0, unsigned k1,
                                    unsigned& x0, unsigned& x1) {
  const unsigned k2 = k0 ^ k1 ^ 0x1BD11BDAu;
  x0 += k0; x1 += k1;
#define TF_RND(r) { x0 += x1; x1 = (x1 << (r)) | (x1 >> (32 - (r))); x1 ^= x0; }
  TF_RND(13) TF_RND(15) TF_RND(26) TF_RND(6)
  x0 += k1; x1 += k2 + 1u;
  TF_RND(17) TF_RND(29) TF_RND(16) TF_RND(24)
  x0 += k2; x1 += k0 + 2u;
  TF_RND(13) TF_RND(15) TF_RND(26) TF_RND(6)
  x0 += k0; x1 += k1 + 3u;
  TF_RND(17) TF_RND(29) TF_RND(16) TF_RND(24)
  x0 += k1; x1 += k2 + 4u;
  TF_RND(13) TF_RND(15) TF_RND(26) TF_RND(6)
  x0 += k2; x1 += k0 + 5u;
#undef TF_RND
}

// Winner key for neuron o spiking at step ts: bit63 marks "candidate";
// bits[32:54] = noise mantissa (monotone in the uniform float);
// low word = NO-1-o (ties break toward smaller o, matching argmax).
__device__ inline unsigned long long winner_key(int ts, int o) {
  const unsigned H = (unsigned)T_STEPS * (unsigned)NO / 2u; // 4194304
  const unsigned i = (unsigned)ts * (unsigned)NO + (unsigned)o;
  unsigned c0 = (i < H) ? i : (i - H);
  unsigned c1 = (i < H) ? (i + H) : i;
  threefry2x32(0u, 42u, c0, c1);
  const unsigned mant = (((i < H) ? c0 : c1) >> 9); // 23 bits
  return (1ull << 63) | ((unsigned long long)mant << 32) |
         (unsigned)(NO - 1 - o);
}

// Block-wide (1024-thread) max-reduce with broadcast. `part` is 16-entry LDS.
__device__ inline unsigned long long
block_max_u64(unsigned long long k, unsigned long long* part) {
  const int tid = (int)threadIdx.x;
#pragma unroll
  for (int off = 32; off >= 1; off >>= 1) {
    const unsigned long long v = __shfl_xor(k, off, 64);
    k = (v > k) ? v : k;
  }
  if ((tid & 63) == 0) part[tid >> 6] = k;
  __syncthreads();
  if (tid == 0) {
    unsigned long long m = 0ull;
#pragma unroll
    for (int j = 0; j < 16; ++j) m = (part[j] > m) ? part[j] : m;
    part[0] = m;
  }
  __syncthreads();
  const unsigned long long m = part[0];
  __syncthreads(); // safe LDS reuse by caller
  return m;
}

// Fused uniform main: 4096 identical blocks, one neuron each. Every block
// (1) issues its 16 KB W-row loads (nontemporal — W is single-use, keep L2
// for x and the write stream), (2) streams 16 KB of output zeros while the
// loads are in flight, (3) finishes the dot + reduce and writes mem row 0
// (always recorded — done starts False) + cur0. Read/write HBM mixing is
// per-block at instruction level; no atomics; exactly 2 occupancy rounds.
__global__ __launch_bounds__(256) void k_main(const float* __restrict__ x,
                                              const float* __restrict__ W,
                                              float* __restrict__ out,
                                              Ws* __restrict__ ws) {
  const int o   = (int)blockIdx.x;   // neuron
  const int tid = (int)threadIdx.x;

  const f4* Wrow = reinterpret_cast<const f4*>(W) + (size_t)o * (NI / 4);
  const f4* xr   = reinterpret_cast<const f4*>(x); // row 0

  // (1) issue all W / x loads first (latency in flight during the stores)
  f4 wv[4], xv[4];
#pragma unroll
  for (int k = 0; k < 4; ++k) {
    const int idx = tid + k * 256;
    wv[k] = __builtin_nontemporal_load(&Wrow[idx]);
    xv[k] = xr[idx];
  }

  // (2) zero stores: global zero-index z in [0, Z4TOT) maps to out float4
  //     index v, skipping mem row 0 (written below).
  f4* o4 = reinterpret_cast<f4*>(out);
  const f4 z = {0.0f, 0.0f, 0.0f, 0.0f};
  const unsigned base = (unsigned)o * 1024u + (unsigned)tid;
#pragma unroll
  for (int k = 0; k < 4; ++k) {
    const unsigned j = base + (unsigned)k * 256u;
    if (j < Z4TOT) {
      const unsigned v = (j < SPK_VEC4) ? j : j + 1024u; // skip mem row 0
      __builtin_nontemporal_store(z, &o4[v]);
    }
  }

  // (3) dot + block reduce
  float acc = 0.0f;
#pragma unroll
  for (int k = 0; k < 4; ++k)
    acc += wv[k].x * xv[k].x + wv[k].y * xv[k].y +
           wv[k].z * xv[k].z + wv[k].w * xv[k].w;
#pragma unroll
  for (int off = 32; off >= 1; off >>= 1) acc += __shfl_xor(acc, off, 64);

  __shared__ float part[4];
  if ((tid & 63) == 0) part[tid >> 6] = acc;
  __syncthreads();
  if (tid == 0) {
    const float cur = part[0] + part[1] + part[2] + part[3];
    out[SPK_FLOATS + o] = cur; // mem row 0
    ws->cur0[o] = cur;
  }
}

// Finish, single block of 1024 threads (4 neurons/thread).
// Fast path: reduce t=0 spiker keys from cur0, write winner one-hot, return.
// General path (gated; never runs on this input): exact in-block emulation of
// the reference scan from t=1 — x row staged in LDS, per-thread dots, mem row
// recorded BEFORE the spike check (matching the reference's record-then-done
// order), block-wide winner reduce, break at the first spiking step. Rows
// past the break stay zero (pre-zeroed by k_main).
__global__ __launch_bounds__(1024) void k_fin(const float* __restrict__ x,
                                              const float* __restrict__ W,
                                              float* __restrict__ spk,
                                              float* __restrict__ mem_rec,
                                              Ws* __restrict__ ws) {
  const int tid = (int)threadIdx.x;
  __shared__ unsigned long long part[16];
  __shared__ float xs[NI];

  float mem[4];
  unsigned long long k = 0ull;
#pragma unroll
  for (int j = 0; j < 4; ++j) {
    const int o = tid + j * 1024;
    const float c = ws->cur0[o];
    mem[j] = c;
    if (c > THRESH) {
      const unsigned long long v = winner_key(0, o);
      k = (v > k) ? v : k;
    }
  }
  unsigned long long m = block_max_u64(k, part);
  if (m != 0ull) { // fast path: spike at t=0
    if (tid == 0) {
      const unsigned o = (unsigned)(NO - 1) - (unsigned)(m & 0xFFFFFFFFull);
      spk[o] = 1.0f; // row 0
    }
    return;
  }

  // ---- general path (correctness-only; performance-irrelevant) ----
  for (int t = 1; t < T_STEPS; ++t) {
    for (int i = tid; i < NI; i += 1024) xs[i] = x[(size_t)t * NI + i];
    __syncthreads();

    unsigned long long kk = 0ull;
#pragma unroll
    for (int j = 0; j < 4; ++j) {
      const int o = tid + j * 1024;
      const float* Wrow = W + (size_t)o * NI;
      float acc = 0.0f;
      for (int i = 0; i < NI; ++i) acc += xs[i] * Wrow[i];
      const float reset = (mem[j] > THRESH) ? THRESH : 0.0f;
      mem[j] = BETA * mem[j] + acc - reset;
      mem_rec[(size_t)t * NO + o] = mem[j]; // recorded before done-check
      if (mem[j] > THRESH) {
        const unsigned long long v = winner_key(t, o);
        kk = (v > kk) ? v : kk;
      }
    }
    __syncthreads(); // xs reuse barrier
    m = block_max_u64(kk, part);
    if (m != 0ull) { // first spiking step: winner, then done -> zeros remain
      if (tid == 0) {
        const unsigned o = (unsigned)(NO - 1) - (unsigned)(m & 0xFFFFFFFFull);
        spk[(size_t)t * NO + o] = 1.0f;
      }
      return;
    }
  }
}

extern "C" void kernel_launch(void* const* d_in, const int* in_sizes, int n_in,
                              void* d_out, int out_size, void* d_ws, size_t ws_size,
                              hipStream_t stream) {
  const float* x = (const float*)d_in[0]; // [T, NI]
  const float* W = (const float*)d_in[1]; // [NO, NI]
  float* spk = (float*)d_out;                          // output 0: [T, NO]
  float* mem = (float*)d_out + (size_t)SPK_FLOATS;     // output 1: [T, NO]
  Ws* ws = (Ws*)d_ws;

  k_main<<<NO, 256, 0, stream>>>(x, W, (float*)d_out, ws);
  k_fin<<<1, 1024, 0, stream>>>(x, W, spk, mem, ws);
}

// Round 9
// 27.148 us; speedup vs baseline: 1.1636x; 1.1636x over previous
//
#include <hip/hip_runtime.h>

#define T_STEPS 2048
#define NI 4096
#define NO 4096

static constexpr float BETA = 0.9f;
static constexpr float THRESH = 1.0f;

#define SPK_FLOATS ((unsigned)T_STEPS * (unsigned)NO)      // 8,388,608
#define SPK_VEC4   (SPK_FLOATS / 4u)                       // 2,097,152
#define TOT_VEC4   (2u * SPK_VEC4)                         // 4,194,304
#define Z4TOT      (TOT_VEC4 - 1024u)                      // skip mem row 0

typedef float f4 __attribute__((ext_vector_type(4)));

// Workspace: just cur0. Fully rewritten every call (no stale-state reliance).
struct Ws {
  float cur0[NO]; // cur at t=0 = x[0]·W[o]
};

// ---- Threefry-2x32, key = (0, 42), matching JAX's threefry2x32 ----
__device__ inline void threefry2x32(unsigned k0, unsigned k1,
                                    unsigned& x0, unsigned& x1) {
  const unsigned k2 = k0 ^ k1 ^ 0x1BD11BDAu;
  x0 += k0; x1 += k1;
#define TF_RND(r) { x0 += x1; x1 = (x1 << (r)) | (x1 >> (32 - (r))); x1 ^= x0; }
  TF_RND(13) TF_RND(15) TF_RND(26) TF_RND(6)
  x0 += k1; x1 += k2 + 1u;
  TF_RND(17) TF_RND(29) TF_RND(16) TF_RND(24)
  x0 += k2; x1 += k0 + 2u;
  TF_RND(13) TF_RND(15) TF_RND(26) TF_RND(6)
  x0 += k0; x1 += k1 + 3u;
  TF_RND(17) TF_RND(29) TF_RND(16) TF_RND(24)
  x0 += k1; x1 += k2 + 4u;
  TF_RND(13) TF_RND(15) TF_RND(26) TF_RND(6)
  x0 += k2; x1 += k0 + 5u;
#undef TF_RND
}

// Winner key for neuron o spiking at step ts: bit63 marks "candidate";
// bits[32:54] = noise mantissa (monotone in the uniform float);
// low word = NO-1-o (ties break toward smaller o, matching argmax).
__device__ inline unsigned long long winner_key(int ts, int o) {
  const unsigned H = (unsigned)T_STEPS * (unsigned)NO / 2u; // 4194304
  const unsigned i = (unsigned)ts * (unsigned)NO + (unsigned)o;
  unsigned c0 = (i < H) ? i : (i - H);
  unsigned c1 = (i < H) ? (i + H) : i;
  threefry2x32(0u, 42u, c0, c1);
  const unsigned mant = (((i < H) ? c0 : c1) >> 9); // 23 bits
  return (1ull << 63) | ((unsigned long long)mant << 32) |
         (unsigned)(NO - 1 - o);
}

// Block-wide (1024-thread) max-reduce with broadcast. `part` is 16-entry LDS.
__device__ inline unsigned long long
block_max_u64(unsigned long long k, unsigned long long* part) {
  const int tid = (int)threadIdx.x;
#pragma unroll
  for (int off = 32; off >= 1; off >>= 1) {
    const unsigned long long v = __shfl_xor(k, off, 64);
    k = (v > k) ? v : k;
  }
  if ((tid & 63) == 0) part[tid >> 6] = k;
  __syncthreads();
  if (tid == 0) {
    unsigned long long m = 0ull;
#pragma unroll
    for (int j = 0; j < 16; ++j) m = (part[j] > m) ? part[j] : m;
    part[0] = m;
  }
  __syncthreads();
  const unsigned long long m = part[0];
  __syncthreads(); // safe LDS reuse by caller
  return m;
}

// Fused main, specialized blocks (R7 structure, 4-neuron GEMV blocks):
//  - bid%3==0 (1024 blocks): GEMV for neurons 4q..4q+3. x row loaded ONCE
//    per thread (was once per neuron in R7 — x was half of all load-issue
//    traffic); all 16 W float4 loads issued up front for max MLP. Plain
//    (cached) loads — W is LLC-resident across graph replays; NT hints on
//    loads defeat that (R8 regression).
//  - bid%3!=0 (2048 blocks): stream non-temporal zeros over spk and mem
//    rows 1..2047 (skipping mem row 0, written by the GEMV blocks).
// Interleaved so read-bound and write-bound blocks share every CU and the
// HBM pipe from the start. No atomics.
__global__ __launch_bounds__(256) void k_main(const float* __restrict__ x,
                                              const float* __restrict__ W,
                                              float* __restrict__ out,
                                              Ws* __restrict__ ws) {
  const unsigned bid = blockIdx.x;
  const unsigned tid = threadIdx.x;
  const unsigned q   = bid / 3u;
  const unsigned r   = bid % 3u;

  if (r != 0u) {
    // ---- zero block zb in [0, 2048) ----
    const unsigned zb = q * 2u + (r - 1u);
    f4* o4 = reinterpret_cast<f4*>(out);
    const f4 z = {0.0f, 0.0f, 0.0f, 0.0f};
    const unsigned base = zb * 2048u + tid;
#pragma unroll
    for (int k = 0; k < 8; ++k) {
      const unsigned j = base + (unsigned)k * 256u;
      if (j < Z4TOT) {
        const unsigned v = (j < SPK_VEC4) ? j : j + 1024u; // skip mem row 0
        __builtin_nontemporal_store(z, &o4[v]);
      }
    }
    return;
  }

  // ---- GEMV block: neurons o0..o0+3 ----
  const int o0 = (int)(q * 4u);
  const f4* xr = reinterpret_cast<const f4*>(x); // row 0

  f4 xv[4];
#pragma unroll
  for (int k = 0; k < 4; ++k) xv[k] = xr[(int)tid + k * 256];

  f4 wv[4][4];
#pragma unroll
  for (int n = 0; n < 4; ++n) {
    const f4* Wrow =
        reinterpret_cast<const f4*>(W) + (size_t)(o0 + n) * (NI / 4);
#pragma unroll
    for (int k = 0; k < 4; ++k) wv[n][k] = Wrow[(int)tid + k * 256];
  }

  __shared__ float part[4][4]; // [wave][neuron]
#pragma unroll
  for (int n = 0; n < 4; ++n) {
    float acc = 0.0f;
#pragma unroll
    for (int k = 0; k < 4; ++k)
      acc += wv[n][k].x * xv[k].x + wv[n][k].y * xv[k].y +
             wv[n][k].z * xv[k].z + wv[n][k].w * xv[k].w;
#pragma unroll
    for (int off = 32; off >= 1; off >>= 1) acc += __shfl_xor(acc, off, 64);
    if ((tid & 63u) == 0u) part[tid >> 6][n] = acc;
  }
  __syncthreads();
  if (tid < 4u) {
    const float cur =
        part[0][tid] + part[1][tid] + part[2][tid] + part[3][tid];
    const int o = o0 + (int)tid;
    out[SPK_FLOATS + o] = cur; // mem row 0 (always recorded; done starts False)
    ws->cur0[o] = cur;
  }
}

// Finish, single block of 1024 threads (4 neurons/thread).
// Fast path: reduce t=0 spiker keys from cur0, write winner one-hot, return.
// General path (gated; never runs on this input): exact in-block emulation of
// the reference scan from t=1 — x row staged in LDS, per-thread dots, mem row
// recorded BEFORE the spike check (matching the reference's record-then-done
// order), block-wide winner reduce, break at the first spiking step. Rows
// past the break stay zero (pre-zeroed by k_main).
__global__ __launch_bounds__(1024) void k_fin(const float* __restrict__ x,
                                              const float* __restrict__ W,
                                              float* __restrict__ spk,
                                              float* __restrict__ mem_rec,
                                              Ws* __restrict__ ws) {
  const int tid = (int)threadIdx.x;
  __shared__ unsigned long long part[16];
  __shared__ float xs[NI];

  float mem[4];
  unsigned long long k = 0ull;
#pragma unroll
  for (int j = 0; j < 4; ++j) {
    const int o = tid + j * 1024;
    const float c = ws->cur0[o];
    mem[j] = c;
    if (c > THRESH) {
      const unsigned long long v = winner_key(0, o);
      k = (v > k) ? v : k;
    }
  }
  unsigned long long m = block_max_u64(k, part);
  if (m != 0ull) { // fast path: spike at t=0
    if (tid == 0) {
      const unsigned o = (unsigned)(NO - 1) - (unsigned)(m & 0xFFFFFFFFull);
      spk[o] = 1.0f; // row 0
    }
    return;
  }

  // ---- general path (correctness-only; performance-irrelevant) ----
  for (int t = 1; t < T_STEPS; ++t) {
    for (int i = tid; i < NI; i += 1024) xs[i] = x[(size_t)t * NI + i];
    __syncthreads();

    unsigned long long kk = 0ull;
#pragma unroll
    for (int j = 0; j < 4; ++j) {
      const int o = tid + j * 1024;
      const float* Wrow = W + (size_t)o * NI;
      float acc = 0.0f;
      for (int i = 0; i < NI; ++i) acc += xs[i] * Wrow[i];
      const float reset = (mem[j] > THRESH) ? THRESH : 0.0f;
      mem[j] = BETA * mem[j] + acc - reset;
      mem_rec[(size_t)t * NO + o] = mem[j]; // recorded before done-check
      if (mem[j] > THRESH) {
        const unsigned long long v = winner_key(t, o);
        kk = (v > kk) ? v : kk;
      }
    }
    __syncthreads(); // xs reuse barrier
    m = block_max_u64(kk, part);
    if (m != 0ull) { // first spiking step: winner, then done -> zeros remain
      if (tid == 0) {
        const unsigned o = (unsigned)(NO - 1) - (unsigned)(m & 0xFFFFFFFFull);
        spk[(size_t)t * NO + o] = 1.0f;
      }
      return;
    }
  }
}

extern "C" void kernel_launch(void* const* d_in, const int* in_sizes, int n_in,
                              void* d_out, int out_size, void* d_ws, size_t ws_size,
                              hipStream_t stream) {
  const float* x = (const float*)d_in[0]; // [T, NI]
  const float* W = (const float*)d_in[1]; // [NO, NI]
  float* spk = (float*)d_out;                          // output 0: [T, NO]
  float* mem = (float*)d_out + (size_t)SPK_FLOATS;     // output 1: [T, NO]
  Ws* ws = (Ws*)d_ws;

  k_main<<<3072, 256, 0, stream>>>(x, W, (float*)d_out, ws);
  k_fin<<<1, 1024, 0, stream>>>(x, W, spk, mem, ws);
}

// Round 10
// 26.123 us; speedup vs baseline: 1.2093x; 1.0392x over previous
//
#include <hip/hip_runtime.h>

#define T_STEPS 2048
#define NI 4096
#define NO 4096

static constexpr float BETA = 0.9f;
static constexpr float THRESH = 1.0f;

#define SPK_FLOATS ((unsigned)T_STEPS * (unsigned)NO)      // 8,388,608
#define SPK_VEC4   (SPK_FLOATS / 4u)                       // 2,097,152
#define TOT_VEC4   (2u * SPK_VEC4)                         // 4,194,304
#define ZB         2048u                                   // zero blocks
#define Z4TOT      (TOT_VEC4 - 1024u)                      // skip mem row 0

typedef float f4 __attribute__((ext_vector_type(4)));

// Workspace: just cur0. Fully rewritten every call (no stale-state reliance).
struct Ws {
  float cur0[NO]; // cur at t=0 = x[0]·W[o]
};

// ---- Threefry-2x32, key = (0, 42), matching JAX's threefry2x32 ----
__device__ inline void threefry2x32(unsigned k0, unsigned k1,
                                    unsigned& x0, unsigned& x1) {
  const unsigned k2 = k0 ^ k1 ^ 0x1BD11BDAu;
  x0 += k0; x1 += k1;
#define TF_RND(r) { x0 += x1; x1 = (x1 << (r)) | (x1 >> (32 - (r))); x1 ^= x0; }
  TF_RND(13) TF_RND(15) TF_RND(26) TF_RND(6)
  x0 += k1; x1 += k2 + 1u;
  TF_RND(17) TF_RND(29) TF_RND(16) TF_RND(24)
  x0 += k2; x1 += k0 + 2u;
  TF_RND(13) TF_RND(15) TF_RND(26) TF_RND(6)
  x0 += k0; x1 += k1 + 3u;
  TF_RND(17) TF_RND(29) TF_RND(16) TF_RND(24)
  x0 += k1; x1 += k2 + 4u;
  TF_RND(13) TF_RND(15) TF_RND(26) TF_RND(6)
  x0 += k2; x1 += k0 + 5u;
#undef TF_RND
}

// Winner key for neuron o spiking at step ts: bit63 marks "candidate";
// bits[32:54] = noise mantissa (monotone in the uniform float);
// low word = NO-1-o (ties break toward smaller o, matching argmax).
__device__ inline unsigned long long winner_key(int ts, int o) {
  const unsigned H = (unsigned)T_STEPS * (unsigned)NO / 2u; // 4194304
  const unsigned i = (unsigned)ts * (unsigned)NO + (unsigned)o;
  unsigned c0 = (i < H) ? i : (i - H);
  unsigned c1 = (i < H) ? (i + H) : i;
  threefry2x32(0u, 42u, c0, c1);
  const unsigned mant = (((i < H) ? c0 : c1) >> 9); // 23 bits
  return (1ull << 63) | ((unsigned long long)mant << 32) |
         (unsigned)(NO - 1 - o);
}

// Block-wide (1024-thread) max-reduce with broadcast. `part` is 16-entry LDS.
__device__ inline unsigned long long
block_max_u64(unsigned long long k, unsigned long long* part) {
  const int tid = (int)threadIdx.x;
#pragma unroll
  for (int off = 32; off >= 1; off >>= 1) {
    const unsigned long long v = __shfl_xor(k, off, 64);
    k = (v > k) ? v : k;
  }
  if ((tid & 63) == 0) part[tid >> 6] = k;
  __syncthreads();
  if (tid == 0) {
    unsigned long long m = 0ull;
#pragma unroll
    for (int j = 0; j < 16; ++j) m = (part[j] > m) ? part[j] : m;
    part[0] = m;
  }
  __syncthreads();
  const unsigned long long m = part[0];
  __syncthreads(); // safe LDS reuse by caller
  return m;
}

// Fused main (best-known configuration, R7): 4096 single-neuron GEMV blocks
// (bid%3 != 2) compute cur0[o] = x[0]·W[o] and write mem row 0 (always
// recorded — done starts False); 2048 zero blocks (bid%3 == 2) stream
// non-temporal zeros over spk and mem rows 1..2047. 2:1 interleave so
// read-bound and write-bound blocks share every CU and the HBM pipe from
// the start. Plain cached W loads (NT load hints regressed — R8: they
// defeat LLC residency across graph replays). No atomics.
__global__ __launch_bounds__(256) void k_main(const float* __restrict__ x,
                                              const float* __restrict__ W,
                                              float* __restrict__ out,
                                              Ws* __restrict__ ws) {
  const unsigned bid = blockIdx.x;
  const unsigned tid = threadIdx.x;
  const unsigned q   = bid / 3u;
  const unsigned r   = bid % 3u;

  if (r == 2u) {
    // ---- zero block q in [0, ZB) ----
    f4* o4 = reinterpret_cast<f4*>(out);
    const f4 z = {0.0f, 0.0f, 0.0f, 0.0f};
    const unsigned base = q * 2048u + tid;
#pragma unroll
    for (int k = 0; k < 8; ++k) {
      const unsigned j = base + (unsigned)k * 256u;
      if (j < Z4TOT) {
        const unsigned v = (j < SPK_VEC4) ? j : j + 1024u; // skip mem row 0
        __builtin_nontemporal_store(z, &o4[v]);
      }
    }
    return;
  }

  // ---- GEMV block: neuron o in [0, NO) ----
  const int o = (int)(q * 2u + r);
  const float4* Wrow = reinterpret_cast<const float4*>(W) + (size_t)o * (NI / 4);
  const float4* xr   = reinterpret_cast<const float4*>(x); // row 0

  float acc = 0.0f;
#pragma unroll
  for (int k = 0; k < 4; ++k) {
    const int idx = (int)tid + k * 256;
    float4 wv = Wrow[idx];
    float4 xv = xr[idx];
    acc += wv.x * xv.x + wv.y * xv.y + wv.z * xv.z + wv.w * xv.w;
  }
#pragma unroll
  for (int off = 32; off >= 1; off >>= 1) acc += __shfl_xor(acc, off, 64);

  __shared__ float part[4];
  if ((tid & 63u) == 0u) part[tid >> 6] = acc;
  __syncthreads();
  if (tid == 0u) {
    const float cur = part[0] + part[1] + part[2] + part[3];
    out[SPK_FLOATS + o] = cur; // mem row 0
    ws->cur0[o] = cur;
  }
}

// Finish, single block of 1024 threads (4 neurons/thread).
// Fast path: reduce t=0 spiker keys from cur0, write winner one-hot, return.
// General path (gated; never runs on this input): exact in-block emulation of
// the reference scan from t=1 — x row staged in LDS, per-thread dots, mem row
// recorded BEFORE the spike check (matching the reference's record-then-done
// order), block-wide winner reduce, break at the first spiking step. Rows
// past the break stay zero (pre-zeroed by k_main).
__global__ __launch_bounds__(1024) void k_fin(const float* __restrict__ x,
                                              const float* __restrict__ W,
                                              float* __restrict__ spk,
                                              float* __restrict__ mem_rec,
                                              Ws* __restrict__ ws) {
  const int tid = (int)threadIdx.x;
  __shared__ unsigned long long part[16];
  __shared__ float xs[NI];

  float mem[4];
  unsigned long long k = 0ull;
#pragma unroll
  for (int j = 0; j < 4; ++j) {
    const int o = tid + j * 1024;
    const float c = ws->cur0[o];
    mem[j] = c;
    if (c > THRESH) {
      const unsigned long long v = winner_key(0, o);
      k = (v > k) ? v : k;
    }
  }
  unsigned long long m = block_max_u64(k, part);
  if (m != 0ull) { // fast path: spike at t=0
    if (tid == 0) {
      const unsigned o = (unsigned)(NO - 1) - (unsigned)(m & 0xFFFFFFFFull);
      spk[o] = 1.0f; // row 0
    }
    return;
  }

  // ---- general path (correctness-only; performance-irrelevant) ----
  for (int t = 1; t < T_STEPS; ++t) {
    for (int i = tid; i < NI; i += 1024) xs[i] = x[(size_t)t * NI + i];
    __syncthreads();

    unsigned long long kk = 0ull;
#pragma unroll
    for (int j = 0; j < 4; ++j) {
      const int o = tid + j * 1024;
      const float* Wrow = W + (size_t)o * NI;
      float acc = 0.0f;
      for (int i = 0; i < NI; ++i) acc += xs[i] * Wrow[i];
      const float reset = (mem[j] > THRESH) ? THRESH : 0.0f;
      mem[j] = BETA * mem[j] + acc - reset;
      mem_rec[(size_t)t * NO + o] = mem[j]; // recorded before done-check
      if (mem[j] > THRESH) {
        const unsigned long long v = winner_key(t, o);
        kk = (v > kk) ? v : kk;
      }
    }
    __syncthreads(); // xs reuse barrier
    m = block_max_u64(kk, part);
    if (m != 0ull) { // first spiking step: winner, then done -> zeros remain
      if (tid == 0) {
        const unsigned o = (unsigned)(NO - 1) - (unsigned)(m & 0xFFFFFFFFull);
        spk[(size_t)t * NO + o] = 1.0f;
      }
      return;
    }
  }
}

extern "C" void kernel_launch(void* const* d_in, const int* in_sizes, int n_in,
                              void* d_out, int out_size, void* d_ws, size_t ws_size,
                              hipStream_t stream) {
  const float* x = (const float*)d_in[0]; // [T, NI]
  const float* W = (const float*)d_in[1]; // [NO, NI]
  float* spk = (float*)d_out;                          // output 0: [T, NO]
  float* mem = (float*)d_out + (size_t)SPK_FLOATS;     // output 1: [T, NO]
  Ws* ws = (Ws*)d_ws;

  k_main<<<NO + (int)ZB, 256, 0, stream>>>(x, W, (float*)d_out, ws);
  k_fin<<<1, 1024, 0, stream>>>(x, W, spk, mem, ws);
}